// Round 16
// baseline (721.671 us; speedup 1.0000x reference)
//
#include <hip/hip_runtime.h>

#define N_NODES 50000
#define N_EDGES 1600000
#define D 32

#define NPB 49                // nodes per bucket; bucket k = dst/49, max 1020
#define NBUCK 1024            // bucket table size (k <= 1020)
#define NAGG 1021             // aggregate blocks = buckets that contain nodes
#define SORT_BLOCKS 128
#define SORT_EPB 12500        // 128 * 12500 = 1.6M exactly
#define LB_STRIDE 1025

#define HIST_BLOCKS 128
#define HIST_EPB 12500
#define HWORDS 12500          // u8 x4 packed counts; 4*12500 = 50000 nodes exactly
#define NORM_HALF 49          // ceil(12500/256)

// ---------------------------------------------------------------------------
// K1: block-private degree histograms, u8x4 packed in LDS (50 KB).
// ---------------------------------------------------------------------------
__global__ __launch_bounds__(256) void hist_kernel(const int* __restrict__ src,
                                                   const int* __restrict__ dst,
                                                   unsigned int* __restrict__ dumpA,
                                                   unsigned int* __restrict__ dumpB) {
    __shared__ unsigned int h[HWORDS];
    int b = blockIdx.x;
    const int* idx = (b < HIST_BLOCKS) ? src : dst;
    unsigned int* dump = (b < HIST_BLOCKS) ? dumpA : dumpB;
    int chunk = (b < HIST_BLOCKS) ? b : b - HIST_BLOCKS;

    int t = threadIdx.x;
    for (int i = t; i < HWORDS; i += 256) h[i] = 0u;
    __syncthreads();
    int e0 = chunk * HIST_EPB;
    for (int i = t; i < HIST_EPB; i += 256) {
        int s = idx[e0 + i];
        atomicAdd(&h[s >> 2], 1u << (8 * (s & 3)));  // LDS, returnless
    }
    __syncthreads();
    unsigned int* o = dump + (size_t)chunk * HWORDS;
    for (int i = t; i < HWORDS; i += 256) o[i] = h[i];
}

// ---------------------------------------------------------------------------
// K2: reduce histograms -> norms; fused xs1 = x * norm_out on the src half.
// ---------------------------------------------------------------------------
__global__ __launch_bounds__(256) void norm_kernel(const unsigned int* __restrict__ dumpA,
                                                   const unsigned int* __restrict__ dumpB,
                                                   float* __restrict__ norm_out,
                                                   float* __restrict__ norm_in,
                                                   const float* __restrict__ x,
                                                   float* __restrict__ xs1) {
    int blk = blockIdx.x;
    bool outs = (blk < NORM_HALF);
    int w = (outs ? blk : blk - NORM_HALF) * 256 + threadIdx.x;
    if (w >= HWORDS) return;
    const unsigned int* dump = outs ? dumpA : dumpB;

    unsigned int a0 = 0, a1 = 0, a2 = 0, a3 = 0;
    for (int b = 0; b < HIST_BLOCKS; ++b) {
        unsigned int v = dump[(size_t)b * HWORDS + w];
        a0 += v & 0xFFu;
        a1 += (v >> 8) & 0xFFu;
        a2 += (v >> 16) & 0xFFu;
        a3 += (v >> 24);
    }
    float n[4];
    n[0] = a0 ? rsqrtf((float)a0) : 0.f;
    n[1] = a1 ? rsqrtf((float)a1) : 0.f;
    n[2] = a2 ? rsqrtf((float)a2) : 0.f;
    n[3] = a3 ? rsqrtf((float)a3) : 0.f;

    int node = 4 * w;
    float* norm = outs ? norm_out : norm_in;
    norm[node + 0] = n[0];
    norm[node + 1] = n[1];
    norm[node + 2] = n[2];
    norm[node + 3] = n[3];

    if (outs) {
        const float4* xin = (const float4*)(x + (size_t)node * D);
        float4* xout = (float4*)(xs1 + (size_t)node * D);
#pragma unroll
        for (int r = 0; r < 4; ++r) {
            float nn = n[r];
#pragma unroll
            for (int q = 0; q < 8; ++q) {
                float4 v = xin[r * 8 + q];
                v.x *= nn; v.y *= nn; v.z *= nn; v.w *= nn;
                xout[r * 8 + q] = v;
            }
        }
    }
}

// ---------------------------------------------------------------------------
// K3: per-block local counting sort by bucket (dst/49). LDS-only.
// ---------------------------------------------------------------------------
__global__ __launch_bounds__(256) void bucket_sort_kernel(const int* __restrict__ src,
                                                          const int* __restrict__ dst,
                                                          unsigned int* __restrict__ pairbuf,
                                                          int* __restrict__ lbase_g) {
    __shared__ unsigned int sorted[SORT_EPB];  // 50 KB
    __shared__ int cnt[NBUCK];
    __shared__ int lbase[NBUCK + 1];
    __shared__ int part[256];

    int t = threadIdx.x;
    int e0 = blockIdx.x * SORT_EPB;

    for (int i = t; i < NBUCK; i += 256) cnt[i] = 0;
    __syncthreads();
    for (int i = t; i < SORT_EPB; i += 256) {
        int d = dst[e0 + i];
        atomicAdd(&cnt[d / NPB], 1);  // LDS, returnless
    }
    __syncthreads();

    int b4 = t * 4;
    int s0 = cnt[b4], s1 = cnt[b4 + 1], s2 = cnt[b4 + 2], s3 = cnt[b4 + 3];
    int mysum = s0 + s1 + s2 + s3;
    part[t] = mysum;
    __syncthreads();
    for (int off = 1; off < 256; off <<= 1) {
        int add = (t >= off) ? part[t - off] : 0;
        __syncthreads();
        part[t] += add;
        __syncthreads();
    }
    int run = part[t] - mysum;
    lbase[b4 + 0] = run;
    lbase[b4 + 1] = run + s0;
    lbase[b4 + 2] = run + s0 + s1;
    lbase[b4 + 3] = run + s0 + s1 + s2;
    if (t == 255) lbase[NBUCK] = part[255];  // == SORT_EPB
    __syncthreads();
    for (int i = t; i < NBUCK; i += 256) cnt[i] = lbase[i];  // cursors
    __syncthreads();

    for (int i = t; i < SORT_EPB; i += 256) {
        int d = dst[e0 + i];
        int s = src[e0 + i];
        int k = d / NPB;
        int pos = atomicAdd(&cnt[k], 1);  // LDS, with return
        sorted[pos] = (unsigned int)s | ((unsigned int)(d - k * NPB) << 16);
    }
    __syncthreads();

    unsigned int* po = pairbuf + (size_t)blockIdx.x * SORT_EPB;
    for (int i = t; i < SORT_EPB; i += 256) po[i] = sorted[i];
    int* lo = lbase_g + blockIdx.x * LB_STRIDE;
    for (int i = t; i <= NBUCK; i += 256) lo[i] = lbase[i];
}

// ---------------------------------------------------------------------------
// K3b: column scan. Single block, 1024 threads; thread k owns bucket k.
// offbuf[b][k] = sum_{b'<b} len[b'][k];  gbase[k] = global bucket base.
// ---------------------------------------------------------------------------
__global__ __launch_bounds__(1024) void colscan_kernel(const int* __restrict__ lbase_g,
                                                       int* __restrict__ offbuf,
                                                       int* __restrict__ gbase) {
    __shared__ int tot[NBUCK];
    int k = threadIdx.x;
    int running = 0;
    for (int b = 0; b < SORT_BLOCKS; ++b) {
        offbuf[b * NBUCK + k] = running;
        running += lbase_g[b * LB_STRIDE + k + 1] - lbase_g[b * LB_STRIDE + k];
    }
    tot[k] = running;
    __syncthreads();
    for (int off = 1; off < NBUCK; off <<= 1) {
        int add = (k >= off) ? tot[k - off] : 0;
        __syncthreads();
        tot[k] += add;
        __syncthreads();
    }
    gbase[k] = tot[k] - running;  // exclusive
    if (k == NBUCK - 1) gbase[NBUCK] = tot[k];
}

// ---------------------------------------------------------------------------
// K3c: scatter local-sorted segments to globally bucket-contiguous pairbuf2.
// Bucket id per entry via precomputed LDS karr (no search, no atomics).
// ---------------------------------------------------------------------------
__global__ __launch_bounds__(256) void gscatter_kernel(const unsigned int* __restrict__ pairbuf,
                                                       const int* __restrict__ lbase_g,
                                                       const int* __restrict__ offbuf,
                                                       const int* __restrict__ gbase,
                                                       unsigned int* __restrict__ pairbuf2) {
    __shared__ int lb[NBUCK + 1];
    __shared__ int tgt[NBUCK];
    __shared__ unsigned short karr[SORT_EPB];  // 25 KB
    int b = blockIdx.x;
    int t = threadIdx.x;
    for (int i = t; i <= NBUCK; i += 256) lb[i] = lbase_g[b * LB_STRIDE + i];
    __syncthreads();
    for (int k = t; k < NBUCK; k += 256) {
        tgt[k] = gbase[k] + offbuf[b * NBUCK + k] - lb[k];
        int e1 = lb[k + 1];
        for (int i = lb[k]; i < e1; ++i) karr[i] = (unsigned short)k;
    }
    __syncthreads();
    const unsigned int* pi = pairbuf + (size_t)b * SORT_EPB;
    for (int i = t; i < SORT_EPB; i += 256) {
        int k = karr[i];
        pairbuf2[tgt[k] + i] = pi[i];  // runs of ~12 consecutive targets
    }
}

// ---------------------------------------------------------------------------
// K4/K5: per-bucket aggregate from CONTIGUOUS edge range + fused epilogue.
// Lane owns a float4 quarter-row: 8 edges per wave instruction, 2x unrolled
// -> 16 edges in flight/wave. LDS acc swizzled (+5*dl words) => ~2-way banks.
// ---------------------------------------------------------------------------
#define AIDX(dl, col) ((dl) * D + (((col) + 5 * (dl)) & 31))

template <int IS_L1>
__global__ __launch_bounds__(256) void aggregate_kernel(const int* __restrict__ gbase,
                                                        const unsigned int* __restrict__ pairbuf2,
                                                        const float4* __restrict__ xs4,
                                                        const float* __restrict__ norm_in,
                                                        const float* __restrict__ norm_out,
                                                        const float* __restrict__ W,
                                                        const float* __restrict__ bias,
                                                        float* __restrict__ out) {
    __shared__ float acc[NPB * D];   // 6272 B, swizzled layout
    __shared__ float sW[D * D];
    __shared__ float sB[D];

    int t = threadIdx.x;
    int k = blockIdx.x;
    int lo = k * NPB;
    int nb = min(NPB, N_NODES - lo);

    for (int i = t; i < NPB * D; i += 256) acc[i] = 0.f;
    for (int i = t; i < D * D; i += 256) sW[i] = W[i];
    if (t < D) sB[t] = bias[t];
    __syncthreads();

    int beg = gbase[k];
    int end = gbase[k + 1];
    int sub = t >> 3;   // edge slot 0..31
    int q = t & 7;      // float4 index within row
    int c0 = q * 4;

    int i = beg + sub;
    for (; i + 32 < end; i += 64) {
        unsigned int pe0 = pairbuf2[i];
        unsigned int pe1 = pairbuf2[i + 32];
        int s0 = pe0 & 0xFFFF, dl0 = pe0 >> 16;
        int s1 = pe1 & 0xFFFF, dl1 = pe1 >> 16;
        float4 v0 = xs4[(size_t)s0 * 8 + q];
        float4 v1 = xs4[(size_t)s1 * 8 + q];
        int rb0 = dl0 * D, sw0 = 5 * dl0;
        atomicAdd(&acc[rb0 + ((c0 + 0 + sw0) & 31)], v0.x);
        atomicAdd(&acc[rb0 + ((c0 + 1 + sw0) & 31)], v0.y);
        atomicAdd(&acc[rb0 + ((c0 + 2 + sw0) & 31)], v0.z);
        atomicAdd(&acc[rb0 + ((c0 + 3 + sw0) & 31)], v0.w);
        int rb1 = dl1 * D, sw1 = 5 * dl1;
        atomicAdd(&acc[rb1 + ((c0 + 0 + sw1) & 31)], v1.x);
        atomicAdd(&acc[rb1 + ((c0 + 1 + sw1) & 31)], v1.y);
        atomicAdd(&acc[rb1 + ((c0 + 2 + sw1) & 31)], v1.z);
        atomicAdd(&acc[rb1 + ((c0 + 3 + sw1) & 31)], v1.w);
    }
    if (i < end) {
        unsigned int pe = pairbuf2[i];
        int s = pe & 0xFFFF, dl = pe >> 16;
        float4 v = xs4[(size_t)s * 8 + q];
        int rb = dl * D, sw = 5 * dl;
        atomicAdd(&acc[rb + ((c0 + 0 + sw) & 31)], v.x);
        atomicAdd(&acc[rb + ((c0 + 1 + sw) & 31)], v.y);
        atomicAdd(&acc[rb + ((c0 + 2 + sw) & 31)], v.z);
        atomicAdd(&acc[rb + ((c0 + 3 + sw) & 31)], v.w);
    }
    __syncthreads();

    if (nb <= 0) return;
    int j = t & 31;
    int r0 = t >> 5;  // 0..7
    for (int r = r0; r < nb; r += 8) {
        int node = lo + r;
        float o = 0.f;
#pragma unroll
        for (int kk = 0; kk < D; ++kk) o += acc[AIDX(r, kk)] * sW[kk * D + j];
        o = o * norm_in[node] + sB[j];
        if (IS_L1) o = fmaxf(o, 0.f) * norm_out[node];
        out[(size_t)node * D + j] = o;
    }
}

// ---------------------------------------------------------------------------
extern "C" void kernel_launch(void* const* d_in, const int* in_sizes, int n_in,
                              void* d_out, int out_size, void* d_ws, size_t ws_size,
                              hipStream_t stream) {
    const float* x  = (const float*)d_in[0];
    const int* src  = (const int*)d_in[1];
    const int* dst  = (const int*)d_in[2];
    const float* W1 = (const float*)d_in[3];
    const float* b1 = (const float*)d_in[4];
    const float* W2 = (const float*)d_in[5];
    const float* b2 = (const float*)d_in[6];
    float* out = (float*)d_out;

    // ---- workspace layout (~33.5 MB) ----
    int* wsI = (int*)d_ws;
    int* lbase_g          = wsI;                             // 131200
    float* norm_out       = (float*)(wsI + 131200);          // 50000
    float* norm_in        = (float*)(wsI + 181200);          // 50000 (pad to 231216)
    unsigned int* pairbuf = (unsigned int*)(wsI + 231216);   // 1.6M
    unsigned int* dumpA   = (unsigned int*)(wsI + 1831216);  // 1.6M (reused: pairbuf2)
    unsigned int* dumpB   = (unsigned int*)(wsI + 3431216);  // 1.6M
    float* xs1            = (float*)(wsI + 5031216);         // 1.6M
    float* xs2            = (float*)(wsI + 6631216);         // 1.6M
    int* offbuf           = wsI + 8231216;                   // 128*1024 = 131072
    int* gbase            = wsI + 8362288;                   // 1025
    unsigned int* pairbuf2 = dumpA;  // dumpA dead after norm_kernel

    // K1: src+dst histograms
    hist_kernel<<<2 * HIST_BLOCKS, 256, 0, stream>>>(src, dst, dumpA, dumpB);
    // K2: norms (+ fused xs1 = x*norm_out)
    norm_kernel<<<2 * NORM_HALF, 256, 0, stream>>>(dumpA, dumpB, norm_out, norm_in, x, xs1);
    // K3: per-block local bucket sort
    bucket_sort_kernel<<<SORT_BLOCKS, 256, 0, stream>>>(src, dst, pairbuf, lbase_g);
    // K3b: cross-block column scan -> offbuf, gbase
    colscan_kernel<<<1, 1024, 0, stream>>>(lbase_g, offbuf, gbase);
    // K3c: scatter to bucket-contiguous global order
    gscatter_kernel<<<SORT_BLOCKS, 256, 0, stream>>>(pairbuf, lbase_g, offbuf, gbase, pairbuf2);
    // K4: layer 1 -> xs2 = relu(h1)*norm_out
    aggregate_kernel<1><<<NAGG, 256, 0, stream>>>(gbase, pairbuf2, (const float4*)xs1,
                                                  norm_in, norm_out, W1, b1, xs2);
    // K5: layer 2 -> final output
    aggregate_kernel<0><<<NAGG, 256, 0, stream>>>(gbase, pairbuf2, (const float4*)xs2,
                                                  norm_in, norm_out, W2, b2, out);
}

// Round 17
// 321.003 us; speedup vs baseline: 2.2482x; 2.2482x over previous
//
#include <hip/hip_runtime.h>

#define N_NODES 50000
#define N_EDGES 1600000
#define D 32

#define HIST_BLOCKS 128
#define HIST_EPB 12500        // 128 * 12500 = 1.6M exactly
#define HWORDS 12500          // u8 x4 packed counts; 4*12500 = 50000 nodes exactly
#define NORM_HALF 49          // ceil(12500/256)
#define NWORDS16 25000        // u16-pair words per block (50000 nodes / 2)
#define HALF_NODES 25000
#define HALF_WORDS 12500

// ---------------------------------------------------------------------------
// K1: block-private degree histograms, u8x4 packed in LDS (50 KB).
// blocks 0..127: src -> dumpA ; blocks 128..255: dst -> dumpB.
// ---------------------------------------------------------------------------
__global__ __launch_bounds__(256) void hist_kernel(const int* __restrict__ src,
                                                   const int* __restrict__ dst,
                                                   unsigned int* __restrict__ dumpA,
                                                   unsigned int* __restrict__ dumpB) {
    __shared__ unsigned int h[HWORDS];
    int b = blockIdx.x;
    const int* idx = (b < HIST_BLOCKS) ? src : dst;
    unsigned int* dump = (b < HIST_BLOCKS) ? dumpA : dumpB;
    int chunk = (b < HIST_BLOCKS) ? b : b - HIST_BLOCKS;

    int t = threadIdx.x;
    for (int i = t; i < HWORDS; i += 256) h[i] = 0u;
    __syncthreads();
    int e0 = chunk * HIST_EPB;
    for (int i = t; i < HIST_EPB; i += 256) {
        int s = idx[e0 + i];
        atomicAdd(&h[s >> 2], 1u << (8 * (s & 3)));  // LDS, returnless
    }
    __syncthreads();
    unsigned int* o = dump + (size_t)chunk * HWORDS;
    for (int i = t; i < HWORDS; i += 256) o[i] = h[i];
}

// ---------------------------------------------------------------------------
// K2: reduce histograms -> norms; fused xs1 = x * norm_out on the src half.
// ---------------------------------------------------------------------------
__global__ __launch_bounds__(256) void norm_kernel(const unsigned int* __restrict__ dumpA,
                                                   const unsigned int* __restrict__ dumpB,
                                                   float* __restrict__ norm_out,
                                                   float* __restrict__ norm_in,
                                                   const float* __restrict__ x,
                                                   float* __restrict__ xs1) {
    int blk = blockIdx.x;
    bool outs = (blk < NORM_HALF);
    int w = (outs ? blk : blk - NORM_HALF) * 256 + threadIdx.x;
    if (w >= HWORDS) return;
    const unsigned int* dump = outs ? dumpA : dumpB;

    unsigned int a0 = 0, a1 = 0, a2 = 0, a3 = 0;
    for (int b = 0; b < HIST_BLOCKS; ++b) {
        unsigned int v = dump[(size_t)b * HWORDS + w];
        a0 += v & 0xFFu;
        a1 += (v >> 8) & 0xFFu;
        a2 += (v >> 16) & 0xFFu;
        a3 += (v >> 24);
    }
    float n[4];
    n[0] = a0 ? rsqrtf((float)a0) : 0.f;
    n[1] = a1 ? rsqrtf((float)a1) : 0.f;
    n[2] = a2 ? rsqrtf((float)a2) : 0.f;
    n[3] = a3 ? rsqrtf((float)a3) : 0.f;

    int node = 4 * w;
    float* norm = outs ? norm_out : norm_in;
    norm[node + 0] = n[0];
    norm[node + 1] = n[1];
    norm[node + 2] = n[2];
    norm[node + 3] = n[3];

    if (outs) {
        const float4* xin = (const float4*)(x + (size_t)node * D);
        float4* xout = (float4*)(xs1 + (size_t)node * D);
#pragma unroll
        for (int r = 0; r < 4; ++r) {
            float nn = n[r];
#pragma unroll
            for (int q = 0; q < 8; ++q) {
                float4 v = xin[r * 8 + q];
                v.x *= nn; v.y *= nn; v.z *= nn; v.w *= nn;
                xout[r * 8 + q] = v;
            }
        }
    }
}

// ---------------------------------------------------------------------------
// K3: nodescan — per-(block,node) EXCLUSIVE u16 offsets (rank-table init)
// offN16[b][n>>1] packs nodes 2m,2m+1; also emits deg[n].
// Thread w owns 4 consecutive nodes (matches u8x4 dump packing).
// ---------------------------------------------------------------------------
__global__ __launch_bounds__(256) void nodescan_kernel(const unsigned int* __restrict__ dumpB,
                                                       unsigned int* __restrict__ offN16,
                                                       int* __restrict__ deg) {
    int w = blockIdx.x * 256 + threadIdx.x;
    if (w >= HWORDS) return;
    unsigned int a0 = 0, a1 = 0, a2 = 0, a3 = 0;
    for (int b = 0; b < HIST_BLOCKS; ++b) {
        offN16[(size_t)b * NWORDS16 + 2 * w]     = a0 | (a1 << 16);
        offN16[(size_t)b * NWORDS16 + 2 * w + 1] = a2 | (a3 << 16);
        unsigned int v = dumpB[(size_t)b * HWORDS + w];
        a0 += v & 0xFFu;
        a1 += (v >> 8) & 0xFFu;
        a2 += (v >> 16) & 0xFFu;
        a3 += (v >> 24);
    }
    int n = 4 * w;
    deg[n + 0] = a0;
    deg[n + 1] = a1;
    deg[n + 2] = a2;
    deg[n + 3] = a3;
}

// ---------------------------------------------------------------------------
// K4: rowscan — exclusive scan of deg -> row_ptr[N+1]. Single 1024-block.
// ---------------------------------------------------------------------------
__global__ __launch_bounds__(1024) void rowscan_kernel(const int* __restrict__ deg,
                                                       int* __restrict__ row_ptr) {
    __shared__ int part[1024];
    int t = threadIdx.x;
    int b0 = t * 49;
    int b1 = min(b0 + 49, N_NODES);
    int s = 0;
    for (int i = b0; i < b1; ++i) s += deg[i];
    part[t] = s;
    __syncthreads();
    for (int off = 1; off < 1024; off <<= 1) {
        int add = (t >= off) ? part[t - off] : 0;
        __syncthreads();
        part[t] += add;
        __syncthreads();
    }
    int run = part[t] - s;
    for (int i = b0; i < b1; ++i) { row_ptr[i] = run; run += deg[i]; }
    if (t == 1023) row_ptr[N_NODES] = part[1023];
}

// ---------------------------------------------------------------------------
// K5: nodescatter — order-preserving counting-sort fill of sorted_src.
// 256 blocks = 128 edge-chunks x 2 node-halves; 50KB LDS u16-pair cursors
// initialized from offN16; rank via packed u16 LDS atomicAdd WITH return.
// slot = row_ptr[d] + rank. Zero global atomics.
// ---------------------------------------------------------------------------
__global__ __launch_bounds__(256) void nodescatter_kernel(const int* __restrict__ src,
                                                          const int* __restrict__ dst,
                                                          const unsigned int* __restrict__ offN16,
                                                          const int* __restrict__ row_ptr,
                                                          int* __restrict__ sorted_src) {
    __shared__ unsigned int cur[HALF_WORDS];  // 50 KB
    int bb = blockIdx.x;
    int chunk = bb >> 1;
    int half = bb & 1;
    int lo = half * HALF_NODES;
    int t = threadIdx.x;

    const unsigned int* base = offN16 + (size_t)chunk * NWORDS16 + half * HALF_WORDS;
    for (int i = t; i < HALF_WORDS; i += 256) cur[i] = base[i];
    __syncthreads();

    int e0 = chunk * HIST_EPB;
    for (int i = t; i < HIST_EPB; i += 256) {
        int d = dst[e0 + i];
        int dl = d - lo;
        if ((unsigned)dl < (unsigned)HALF_NODES) {
            int sh = (d & 1) * 16;
            unsigned int old = atomicAdd(&cur[dl >> 1], 1u << sh);  // LDS, with return
            int rank = (old >> sh) & 0xFFFF;
            sorted_src[row_ptr[d] + rank] = src[e0 + i];
        }
    }
}

// ---------------------------------------------------------------------------
// K6/K7: register-accumulate CSR aggregate + fused norm*GEMM+bias(+relu).
// 8 nodes/block, 6250 blocks (25K waves TLP). Proven-fast structure (r2/r3).
// ---------------------------------------------------------------------------
template <int IS_L1>
__global__ __launch_bounds__(256) void aggregate_kernel(const int* __restrict__ row_ptr,
                                                        const int* __restrict__ sorted_src,
                                                        const float* __restrict__ xs,
                                                        const float* __restrict__ norm_in,
                                                        const float* __restrict__ norm_out,
                                                        const float* __restrict__ W,
                                                        const float* __restrict__ bias,
                                                        float* __restrict__ out) {
    __shared__ float sW[D * D];
    __shared__ float sRow[8][D];

    int t = threadIdx.x;
    int r = t >> 5;   // local node 0..7
    int j = t & 31;   // feature
    int node = blockIdx.x * 8 + r;

    for (int k = t; k < D * D; k += 256) sW[k] = W[k];

    float acc = 0.f;
    if (node < N_NODES) {
        int beg = row_ptr[node];
        int end = row_ptr[node + 1];
#pragma unroll 4
        for (int e = beg; e < end; ++e) {
            int s = sorted_src[e];          // uniform across the 32-thread group
            acc += xs[(size_t)s * D + j];   // coalesced 128B row gather
        }
        acc *= norm_in[node];
    }
    sRow[r][j] = acc;
    __syncthreads();

    if (node >= N_NODES) return;

    float o = bias[j];
#pragma unroll
    for (int k = 0; k < D; ++k) o += sRow[r][k] * sW[k * D + j];

    if (IS_L1) o = fmaxf(o, 0.f) * norm_out[node];
    out[(size_t)node * D + j] = o;
}

// ---------------------------------------------------------------------------
extern "C" void kernel_launch(void* const* d_in, const int* in_sizes, int n_in,
                              void* d_out, int out_size, void* d_ws, size_t ws_size,
                              hipStream_t stream) {
    const float* x  = (const float*)d_in[0];
    const int* src  = (const int*)d_in[1];
    const int* dst  = (const int*)d_in[2];
    const float* W1 = (const float*)d_in[3];
    const float* b1 = (const float*)d_in[4];
    const float* W2 = (const float*)d_in[5];
    const float* b2 = (const float*)d_in[6];
    float* out = (float*)d_out;

    // ---- workspace layout (~45.6 MB) ----
    int* wsI = (int*)d_ws;
    unsigned int* dumpA  = (unsigned int*)wsI;                 // 1.6M words
    unsigned int* dumpB  = (unsigned int*)(wsI + 1600000);     // 1.6M
    unsigned int* offN16 = (unsigned int*)(wsI + 3200000);     // 128*25000 = 3.2M
    int* deg             = wsI + 6400000;                      // 50,016
    int* row_ptr         = wsI + 6450016;                      // 50,016
    int* sorted_src      = wsI + 6500032;                      // 1.6M
    float* xs1           = (float*)(wsI + 8100032);            // 1.6M
    float* xs2           = (float*)(wsI + 9700032);            // 1.6M
    float* norm_out      = (float*)(wsI + 11300032);           // 50,000
    float* norm_in       = (float*)(wsI + 11350032);           // 50,000

    // K1: src+dst histograms
    hist_kernel<<<2 * HIST_BLOCKS, 256, 0, stream>>>(src, dst, dumpA, dumpB);
    // K2: norms (+ fused xs1 = x*norm_out)
    norm_kernel<<<2 * NORM_HALF, 256, 0, stream>>>(dumpA, dumpB, norm_out, norm_in, x, xs1);
    // K3: per-(block,node) u16 offsets + deg
    nodescan_kernel<<<NORM_HALF, 256, 0, stream>>>(dumpB, offN16, deg);
    // K4: deg -> row_ptr
    rowscan_kernel<<<1, 1024, 0, stream>>>(deg, row_ptr);
    // K5: counting-sort fill (order-preserving, no global atomics)
    nodescatter_kernel<<<256, 256, 0, stream>>>(src, dst, offN16, row_ptr, sorted_src);
    // K6: layer 1 -> xs2 = relu(h1)*norm_out
    aggregate_kernel<1><<<(N_NODES + 7) / 8, 256, 0, stream>>>(row_ptr, sorted_src, xs1,
                                                               norm_in, norm_out, W1, b1, xs2);
    // K7: layer 2 -> final output
    aggregate_kernel<0><<<(N_NODES + 7) / 8, 256, 0, stream>>>(row_ptr, sorted_src, xs2,
                                                               norm_in, norm_out, W2, b2, out);
}